// Round 11
// baseline (398.801 us; speedup 1.0000x reference)
//
#include <hip/hip_runtime.h>
#include <hip/hip_bf16.h>
#include <math.h>

// Problem constants
#define LYR 2
#define DIM 128
#define NH 4
#define HD 32
#define BB 2
#define NN 4096
#define MROWS (BB * NN)          // 8192
#define R2 0.0625f               // (WINDOW/2)^2
#define BN_EPS 1e-5f
#define CLOG2E 0.25503594f       // (1/sqrt(32)) * log2(e)
#define NCH 4                    // KV-split chunks
#define CHLEN (NN / NCH)         // 1024 keys per chunk

typedef __attribute__((ext_vector_type(4))) float f32x4;
typedef __attribute__((ext_vector_type(8))) short bf16x8;
typedef __attribute__((ext_vector_type(4))) short bf16x4;

static __device__ inline unsigned short f2bf(float f) {
  union { float f; unsigned u; } v; v.f = f;
  unsigned r = v.u + 0x7FFFu + ((v.u >> 16) & 1u);   // round-to-nearest-even
  return (unsigned short)(r >> 16);
}

static __device__ inline float exp2_fast(float x) {
#if defined(__has_builtin)
#if __has_builtin(__builtin_amdgcn_exp2f)
  return __builtin_amdgcn_exp2f(x);
#else
  return exp2f(x);
#endif
#else
  return exp2f(x);
#endif
}

static __device__ inline unsigned cvt_pk_bf16(float lo, float hi) {
  unsigned r;
  asm volatile("v_cvt_pk_bf16_f32 %0, %1, %2" : "=v"(r) : "v"(lo), "v"(hi));
  return r;
}

// ---------------------------------------------------------------------------
// Weight prep: fp32 W[K][N] -> bf16 W^T[N][K]; Wq (and its bias) pre-scaled by
// CLOG2E so QK^T comes out in exp2 domain. Also builds qkv bias concat [2][384].
__global__ __launch_bounds__(256) void wprep_k(const float* __restrict__ Wq,
                                               const float* __restrict__ Wk,
                                               const float* __restrict__ Wv,
                                               const float* __restrict__ Wo,
                                               const float* __restrict__ L1,
                                               const float* __restrict__ L2,
                                               const float* __restrict__ Wqb,
                                               const float* __restrict__ Wkb,
                                               const float* __restrict__ Wvb,
                                               short* __restrict__ wT,
                                               float* __restrict__ qkvb) {
  const int id = blockIdx.x;
  const int l = id >> 7, r = id & 127;
  const size_t lbase = (size_t)l * 131072;
  const float* src; short* dst; int K, N, tk, tn;
  float mult = 1.0f;
  if (r < 64) {
    const int m = r >> 4, tile = r & 15;
    if (m == 0)      { src = Wq + (size_t)l * 16384; mult = CLOG2E; }
    else if (m == 1) src = Wk + (size_t)l * 16384;
    else if (m == 2) src = Wv + (size_t)l * 16384;
    else             src = Wo + (size_t)l * 16384;
    dst = wT + lbase + (size_t)m * 16384;
    K = 128; N = 128; tk = tile >> 2; tn = tile & 3;
  } else if (r < 96) {
    const int tile = r - 64;
    src = L1 + (size_t)l * 32768; dst = wT + lbase + 65536;
    K = 128; N = 256; tk = tile >> 3; tn = tile & 7;
  } else {
    const int tile = r - 96;
    src = L2 + (size_t)l * 32768; dst = wT + lbase + 98304;
    K = 256; N = 128; tk = tile >> 2; tn = tile & 3;
  }
  __shared__ float tl[32][33];
  const int t = threadIdx.x;
  const int rr = t >> 3, c4 = (t & 7) * 4;
  float4 vv = *(const float4*)(src + (size_t)(tk * 32 + rr) * N + tn * 32 + c4);
  tl[rr][c4 + 0] = vv.x; tl[rr][c4 + 1] = vv.y;
  tl[rr][c4 + 2] = vv.z; tl[rr][c4 + 3] = vv.w;
  __syncthreads();
  bf16x4 o4;
  o4[0] = (short)f2bf(tl[c4 + 0][rr] * mult);
  o4[1] = (short)f2bf(tl[c4 + 1][rr] * mult);
  o4[2] = (short)f2bf(tl[c4 + 2][rr] * mult);
  o4[3] = (short)f2bf(tl[c4 + 3][rr] * mult);
  *(bf16x4*)(dst + (size_t)(tn * 32 + rr) * K + tk * 32 + c4) = o4;
  // bias concat (one block per layer does it)
  if (r == 0) {
    for (int i = t; i < 384; i += 256) {
      float bv;
      if (i < 128)      bv = Wqb[l * 128 + i] * CLOG2E;
      else if (i < 256) bv = Wkb[l * 128 + i - 128];
      else              bv = Wvb[l * 128 + i - 256];
      qkvb[l * 384 + i] = bv;
    }
  }
}

// ---------------------------------------------------------------------------
// Copy x -> out, accumulate BN stats, AND build packed pos table
// pposG[b*N+n] = {x, y, -0.5*|p|^2, 0}.
__global__ __launch_bounds__(256) void copy_stats_k(const float* __restrict__ x,
                                                    float* __restrict__ out,
                                                    float* __restrict__ sums,
                                                    const float* __restrict__ pos,
                                                    float* __restrict__ pposG) {
  __shared__ float ss[8][128], sq[8][128];
  const int t = threadIdx.x;
  const int c4 = (t & 31) * 4, rg = t >> 5;
  const size_t base = (size_t)blockIdx.x * (32 * DIM);
  float s0 = 0.f, s1 = 0.f, s2 = 0.f, s3 = 0.f;
  float q0 = 0.f, q1 = 0.f, q2 = 0.f, q3 = 0.f;
  for (int r = rg; r < 32; r += 8) {
    float4 v = *(const float4*)&x[base + (size_t)r * DIM + c4];
    *(float4*)&out[base + (size_t)r * DIM + c4] = v;
    s0 += v.x; q0 += v.x * v.x;
    s1 += v.y; q1 += v.y * v.y;
    s2 += v.z; q2 += v.z * v.z;
    s3 += v.w; q3 += v.w * v.w;
  }
  if (t < 32) {
    const int row = blockIdx.x * 32 + t;
    float2 pp2 = *(const float2*)&pos[(size_t)row * 2];
    float4 o4 = make_float4(pp2.x, pp2.y, -0.5f * (pp2.x * pp2.x + pp2.y * pp2.y), 0.f);
    *(float4*)&pposG[(size_t)row * 4] = o4;
  }
  ss[rg][c4 + 0] = s0; sq[rg][c4 + 0] = q0;
  ss[rg][c4 + 1] = s1; sq[rg][c4 + 1] = q1;
  ss[rg][c4 + 2] = s2; sq[rg][c4 + 2] = q2;
  ss[rg][c4 + 3] = s3; sq[rg][c4 + 3] = q3;
  __syncthreads();
  if (t < 128) {
    float S = 0.f, Q = 0.f;
#pragma unroll
    for (int r2 = 0; r2 < 8; r2++) { S += ss[r2][t]; Q += sq[r2][t]; }
    atomicAdd(&sums[t], S);
    atomicAdd(&sums[128 + t], Q);
  }
}

// ---------------------------------------------------------------------------
// bf16 MFMA GEMM. WT bf16 [Nn][K]. BM=BN=64, BK=64, 256 thr.
// ABN=true: A is fp32 Af[M][K] normalized on the fly (BN fused).
// MODE 0: fp32 out = acc + bias + res, AND fused BN-stats into statsums.
// MODE 1: bf16 row-major out stride 256 (optional RELU) -- FFN1 only.
// MODE 3: fused QKV split (q | k | transposed head-major v).
template <int MODE, bool RELU, bool ABN>
__global__ __launch_bounds__(256) void gemm_bf_k(const short* __restrict__ A,
                                                 const float* __restrict__ Af,
                                                 const float* __restrict__ stats,
                                                 const float* __restrict__ gma,
                                                 const float* __restrict__ btaN,
                                                 const short* __restrict__ WT,
                                                 const float* __restrict__ bias,
                                                 const float* res,
                                                 float* Cf,
                                                 short* __restrict__ Cb,
                                                 float* __restrict__ statsums,
                                                 int K) {
  __shared__ short a_s[64 * 80];
  __shared__ short w_s[64 * 80];
  __shared__ float sc_s[128], sh_s[128];
  const int t = threadIdx.x, w = t >> 6, lane = t & 63, g = lane >> 4, i16 = lane & 15;
  const int bm = blockIdx.x * 64, bn = blockIdx.y * 64;
  const int sr = t >> 2, sc = (t & 3) * 8, c16 = (t & 3) * 16;
  const size_t MN = (size_t)MROWS * DIM;
  if (ABN) {
    if (t < 128) {
      const float inv = 1.0f / (float)MROWS;
      const float mu = stats[t] * inv;
      const float var = stats[128 + t] * inv - mu * mu;
      const float rs = rsqrtf(var + BN_EPS);
      const float s = rs * gma[t];
      sc_s[t] = s;
      sh_s[t] = btaN[t] - mu * s;
    }
  }
  f32x4 acc[4];
#pragma unroll
  for (int ct = 0; ct < 4; ct++) acc[ct] = (f32x4){0.f, 0.f, 0.f, 0.f};
  for (int k0 = 0; k0 < K; k0 += 64) {
    __syncthreads();
    if (ABN) {
      const float* ap = Af + (size_t)(bm + sr) * K + k0 + c16;
      float4 x0 = *(const float4*)ap, x1 = *(const float4*)(ap + 4);
      float4 x2 = *(const float4*)(ap + 8), x3 = *(const float4*)(ap + 12);
      const int kb = k0 + c16;
      bf16x8 o0, o1;
      o0[0] = (short)f2bf(x0.x * sc_s[kb + 0]  + sh_s[kb + 0]);
      o0[1] = (short)f2bf(x0.y * sc_s[kb + 1]  + sh_s[kb + 1]);
      o0[2] = (short)f2bf(x0.z * sc_s[kb + 2]  + sh_s[kb + 2]);
      o0[3] = (short)f2bf(x0.w * sc_s[kb + 3]  + sh_s[kb + 3]);
      o0[4] = (short)f2bf(x1.x * sc_s[kb + 4]  + sh_s[kb + 4]);
      o0[5] = (short)f2bf(x1.y * sc_s[kb + 5]  + sh_s[kb + 5]);
      o0[6] = (short)f2bf(x1.z * sc_s[kb + 6]  + sh_s[kb + 6]);
      o0[7] = (short)f2bf(x1.w * sc_s[kb + 7]  + sh_s[kb + 7]);
      o1[0] = (short)f2bf(x2.x * sc_s[kb + 8]  + sh_s[kb + 8]);
      o1[1] = (short)f2bf(x2.y * sc_s[kb + 9]  + sh_s[kb + 9]);
      o1[2] = (short)f2bf(x2.z * sc_s[kb + 10] + sh_s[kb + 10]);
      o1[3] = (short)f2bf(x2.w * sc_s[kb + 11] + sh_s[kb + 11]);
      o1[4] = (short)f2bf(x3.x * sc_s[kb + 12] + sh_s[kb + 12]);
      o1[5] = (short)f2bf(x3.y * sc_s[kb + 13] + sh_s[kb + 13]);
      o1[6] = (short)f2bf(x3.z * sc_s[kb + 14] + sh_s[kb + 14]);
      o1[7] = (short)f2bf(x3.w * sc_s[kb + 15] + sh_s[kb + 15]);
      *(bf16x8*)&a_s[sr * 80 + c16] = o0;
      *(bf16x8*)&a_s[sr * 80 + c16 + 8] = o1;
    } else {
      *(bf16x8*)&a_s[sr * 80 + sc]      = *(const bf16x8*)(A + (size_t)(bm + sr) * K + k0 + sc);
      *(bf16x8*)&a_s[sr * 80 + sc + 32] = *(const bf16x8*)(A + (size_t)(bm + sr) * K + k0 + sc + 32);
    }
    *(bf16x8*)&w_s[sr * 80 + sc]      = *(const bf16x8*)(WT + (size_t)(bn + sr) * K + k0 + sc);
    *(bf16x8*)&w_s[sr * 80 + sc + 32] = *(const bf16x8*)(WT + (size_t)(bn + sr) * K + k0 + sc + 32);
    __syncthreads();
#pragma unroll
    for (int ks = 0; ks < 2; ks++) {
      bf16x8 af = *(const bf16x8*)&a_s[(16 * w + i16) * 80 + ks * 32 + 8 * g];
#pragma unroll
      for (int ct = 0; ct < 4; ct++) {
        bf16x8 wf = *(const bf16x8*)&w_s[(ct * 16 + i16) * 80 + ks * 32 + 8 * g];
        acc[ct] = __builtin_amdgcn_mfma_f32_16x16x32_bf16(af, wf, acc[ct], 0, 0, 0);
      }
    }
  }
  float s_acc[4], q_acc[4];
#pragma unroll
  for (int ct = 0; ct < 4; ct++) {
    const int col = bn + ct * 16 + i16;
    const float bv = bias[col];
    if (MODE == 3) {
      const int row0 = bm + 16 * w + 4 * g;
      if (col < 256) {
        short* dstb = (col < 128) ? Cb : (Cb + MN);
        const int cc = col & 127;
#pragma unroll
        for (int r = 0; r < 4; r++)
          dstb[(size_t)(row0 + r) * DIM + cc] = (short)f2bf(acc[ct][r] + bv);
      } else {
        const int b_ = row0 >> 12, n_ = row0 & (NN - 1);
        const int hh = (col - 256) >> 5, dd = (col - 256) & 31;
        bf16x4 o4;
#pragma unroll
        for (int r = 0; r < 4; r++) o4[r] = (short)f2bf(acc[ct][r] + bv);
        *(bf16x4*)(Cb + 2 * MN + ((size_t)(b_ * NH + hh) * HD + dd) * NN + n_) = o4;
      }
    } else if (MODE == 0) {
      float ssum = 0.f, qsum = 0.f;
#pragma unroll
      for (int r = 0; r < 4; r++) {
        const int row = bm + 16 * w + 4 * g + r;
        float vv = acc[ct][r] + bv + res[(size_t)row * DIM + col];
        Cf[(size_t)row * DIM + col] = vv;
        ssum += vv; qsum += vv * vv;
      }
      s_acc[ct] = ssum; q_acc[ct] = qsum;
    } else {
#pragma unroll
      for (int r = 0; r < 4; r++) {
        const int row = bm + 16 * w + 4 * g + r;
        float vv = acc[ct][r] + bv;
        if (RELU) vv = fmaxf(vv, 0.f);
        Cb[(size_t)row * (size_t)256 + col] = (short)f2bf(vv);  // MODE1 only (Nn=256)
      }
    }
  }
  if (MODE == 0) {
#pragma unroll
    for (int ct = 0; ct < 4; ct++) {
      s_acc[ct] += __shfl_xor(s_acc[ct], 16, 64);
      s_acc[ct] += __shfl_xor(s_acc[ct], 32, 64);
      q_acc[ct] += __shfl_xor(q_acc[ct], 16, 64);
      q_acc[ct] += __shfl_xor(q_acc[ct], 32, 64);
    }
    float* bs = (float*)a_s;
    __syncthreads();
    if (t < 128) bs[t] = 0.f;
    __syncthreads();
    if (lane < 16) {
#pragma unroll
      for (int ct = 0; ct < 4; ct++) {
        atomicAdd(&bs[ct * 16 + i16], s_acc[ct]);
        atomicAdd(&bs[64 + ct * 16 + i16], q_acc[ct]);
      }
    }
    __syncthreads();
    if (t < 64) {
      atomicAdd(&statsums[bn + t], bs[t]);
      atomicAdd(&statsums[128 + bn + t], bs[64 + t]);
    }
  }
}

// ---------------------------------------------------------------------------
// RoPE in place on bf16 q,k (layer 0). q is pre-scaled; rotation commutes.
__global__ __launch_bounds__(256) void rope_bf_k(short* __restrict__ q,
                                                 short* __restrict__ kk,
                                                 const float* __restrict__ pos) {
  const int idx = blockIdx.x * 256 + threadIdx.x;   // 32768
  const int row = idx >> 2, hh = idx & 3;
  const float2 pp = *(const float2*)&pos[(size_t)row * 2];
  short* qp = q + (size_t)row * DIM + hh * HD;
  short* kp = kk + (size_t)row * DIM + hh * HD;
  bf16x8 qv[4], kv[4];
#pragma unroll
  for (int u = 0; u < 4; u++) {
    qv[u] = *(const bf16x8*)(qp + 8 * u);
    kv[u] = *(const bf16x8*)(kp + 8 * u);
  }
#pragma unroll
  for (int lp = 0; lp < 16; lp++) {
    const int p = hh * 16 + lp;
    const float coord = (p < 32) ? pp.x : pp.y;
    const int f = p & 31;
    float sn, cs;
    __sincosf(3.14159265358979323846f * (float)(f + 1) * coord, &sn, &cs);
    const int u = lp >> 2, e = (lp & 3) * 2;
    const float a0 = __uint_as_float(((unsigned)(unsigned short)qv[u][e]) << 16);
    const float a1 = __uint_as_float(((unsigned)(unsigned short)qv[u][e + 1]) << 16);
    qv[u][e]     = (short)f2bf(cs * a0 - sn * a1);
    qv[u][e + 1] = (short)f2bf(cs * a1 + sn * a0);
    const float b0 = __uint_as_float(((unsigned)(unsigned short)kv[u][e]) << 16);
    const float b1 = __uint_as_float(((unsigned)(unsigned short)kv[u][e + 1]) << 16);
    kv[u][e]     = (short)f2bf(cs * b0 - sn * b1);
    kv[u][e + 1] = (short)f2bf(cs * b1 + sn * b0);
  }
#pragma unroll
  for (int u = 0; u < 4; u++) {
    *(bf16x8*)(qp + 8 * u) = qv[u];
    *(bf16x8*)(kp + 8 * u) = kv[u];
  }
}

// ---------------------------------------------------------------------------
// Barrier-free LDS-free MFMA attention. KV-split partials, no online max.
// Wave = 32 queries (2 groups of 16); block = 4 independent waves.
// Permuted K-row trick: QK A-operand rows are loaded in order
//   j(jt, r') = 32*(jt>>1) + 8*(r'>>2) + 4*(jt&1) + (r'&3)
// so lane (g,i16)'s QK output quads are exactly the PV B-fragment it needs:
// pack(jt0)||pack(jt1) covers j = 8g..8g+7 (jh=0); jt2||jt3 covers jh=1.
// PV computes O^T = mfma(A = V^T rows d, B = P^T), V^T read from global.
__global__ __launch_bounds__(256) void attn5_k(const short* __restrict__ q,
                                               const short* __restrict__ k,
                                               const short* __restrict__ vt,
                                               const float* __restrict__ pposG,
                                               float* __restrict__ accP,
                                               float* __restrict__ lP) {
  const int bh = blockIdx.y, b = bh >> 2, h = bh & 3;
  const int ch = blockIdx.z;
  const int kbeg = ch * CHLEN;
  const int t = threadIdx.x, w = t >> 6, lane = t & 63, g = lane >> 4, i16 = lane & 15;
  const int q0w = blockIdx.x * 128 + w * 32;
  const short* kp = k + (size_t)b * NN * DIM + h * HD;
  const short* vp = vt + (size_t)bh * HD * NN;
  const float4* pp = (const float4*)pposG + (size_t)b * NN;

  // Q fragments + query positions (2 groups of 16 queries)
  bf16x8 qf[2];
  float qx[2], qy[2], ci[2];
#pragma unroll
  for (int a = 0; a < 2; a++) {
    const int nq = q0w + 16 * a + i16;
    qf[a] = *(const bf16x8*)(q + (size_t)(b * NN + nq) * DIM + h * HD + 8 * g);
    const float4 qp4 = pp[nq];
    qx[a] = qp4.x; qy[a] = qp4.y;
    ci[a] = -qp4.z - 0.5f * R2;     // 0.5|q|^2 - 0.5 R2
  }
  const int jbase = 8 * (i16 >> 2) + (i16 & 3);   // permuted K-row base
  f32x4 acc[2][2];
#pragma unroll
  for (int a = 0; a < 2; a++)
#pragma unroll
    for (int dh = 0; dh < 2; dh++) acc[a][dh] = (f32x4){0.f, 0.f, 0.f, 0.f};
  float lr[2] = {0.f, 0.f};
  const f32x4 zf = {0.f, 0.f, 0.f, 0.f};

  for (int k0 = kbeg; k0 < kbeg + CHLEN; k0 += 64) {
    // K fragments, permuted row order (offsets 0,4,32,36 from jbase)
    bf16x8 kf[4];
    kf[0] = *(const bf16x8*)(kp + (size_t)(k0 + jbase + 0) * DIM + 8 * g);
    kf[1] = *(const bf16x8*)(kp + (size_t)(k0 + jbase + 4) * DIM + 8 * g);
    kf[2] = *(const bf16x8*)(kp + (size_t)(k0 + jbase + 32) * DIM + 8 * g);
    kf[3] = *(const bf16x8*)(kp + (size_t)(k0 + jbase + 36) * DIM + 8 * g);

    // QK^T (swapped): sx[a][jt][r] = S2[j = 32(jt>>1)+8g+4(jt&1)+r][query i16]
    f32x4 sx[2][4];
#pragma unroll
    for (int jt = 0; jt < 4; jt++) {
      sx[0][jt] = __builtin_amdgcn_mfma_f32_16x16x32_bf16(kf[jt], qf[0], zf, 0, 0, 0);
      sx[1][jt] = __builtin_amdgcn_mfma_f32_16x16x32_bf16(kf[jt], qf[1], zf, 0, 0, 0);
    }

    // mask + exp2 + pack (P stays in registers; quads already PV-ordered)
    unsigned pk[2][8];
#pragma unroll
    for (int jt = 0; jt < 4; jt++) {
      const int jo = k0 + ((jt >> 1) << 5) + ((jt & 1) << 2) + 8 * g;
      float4 pj0 = pp[jo + 0], pj1 = pp[jo + 1], pj2 = pp[jo + 2], pj3 = pp[jo + 3];
#pragma unroll
      for (int a = 0; a < 2; a++) {
        float p0 = exp2_fast(sx[a][jt][0]);
        float p1 = exp2_fast(sx[a][jt][1]);
        float p2 = exp2_fast(sx[a][jt][2]);
        float p3 = exp2_fast(sx[a][jt][3]);
        p0 = (fmaf(qx[a], pj0.x, fmaf(qy[a], pj0.y, pj0.z)) >= ci[a]) ? p0 : 0.f;
        p1 = (fmaf(qx[a], pj1.x, fmaf(qy[a], pj1.y, pj1.z)) >= ci[a]) ? p1 : 0.f;
        p2 = (fmaf(qx[a], pj2.x, fmaf(qy[a], pj2.y, pj2.z)) >= ci[a]) ? p2 : 0.f;
        p3 = (fmaf(qx[a], pj3.x, fmaf(qy[a], pj3.y, pj3.z)) >= ci[a]) ? p3 : 0.f;
        lr[a] += (p0 + p1) + (p2 + p3);
        pk[a][jt * 2 + 0] = cvt_pk_bf16(p0, p1);
        pk[a][jt * 2 + 1] = cvt_pk_bf16(p2, p3);
      }
    }

    // PV: O^T[d][i] += V^T[d][j] P^T[j][i]; B-frag = own packed quads
#pragma unroll
    for (int jh = 0; jh < 2; jh++) {
      union { unsigned u[4]; bf16x8 v; } pf0, pf1;
#pragma unroll
      for (int u = 0; u < 4; u++) { pf0.u[u] = pk[0][jh * 4 + u]; pf1.u[u] = pk[1][jh * 4 + u]; }
#pragma unroll
      for (int dh = 0; dh < 2; dh++) {
        bf16x8 vf = *(const bf16x8*)(vp + (size_t)(dh * 16 + i16) * NN + k0 + jh * 32 + 8 * g);
        acc[0][dh] = __builtin_amdgcn_mfma_f32_16x16x32_bf16(vf, pf0.v, acc[0][dh], 0, 0, 0);
        acc[1][dh] = __builtin_amdgcn_mfma_f32_16x16x32_bf16(vf, pf1.v, acc[1][dh], 0, 0, 0);
      }
    }
  }

  // epilogue: unnormalized partials
#pragma unroll
  for (int a = 0; a < 2; a++) {
    lr[a] += __shfl_xor(lr[a], 16, 64);
    lr[a] += __shfl_xor(lr[a], 32, 64);
    if (lane < 16)
      lP[(size_t)(ch * 8 + bh) * NN + q0w + 16 * a + lane] = lr[a];
    float* ap = accP + ((size_t)(ch * 8 + bh) * NN + q0w + 16 * a + i16) * HD;
#pragma unroll
    for (int dh = 0; dh < 2; dh++)
#pragma unroll
      for (int r = 0; r < 4; r++)
        ap[dh * 16 + 4 * g + r] = acc[a][dh][r];
  }
}

// ---------------------------------------------------------------------------
// Combine KV-split partials: O = sum_c acc / sum_c l, write bf16 interleaved.
__global__ __launch_bounds__(256) void attn_comb_k(const float* __restrict__ accP,
                                                   const float* __restrict__ lP,
                                                   short* __restrict__ ob) {
  const int idx = blockIdx.x * 256 + threadIdx.x;   // 262144
  const int b = idx >> 17;
  const int n = (idx >> 5) & (NN - 1);
  const int hd = idx & 31;
  const int h = hd >> 3, d4 = (hd & 7) * 4;
  const int bh = b * NH + h;
  float ax = 0.f, ay = 0.f, az = 0.f, aw = 0.f, l = 0.f;
#pragma unroll
  for (int c = 0; c < NCH; c++) {
    const float4 v = *(const float4*)&accP[((size_t)(c * 8 + bh) * NN + n) * HD + d4];
    ax += v.x; ay += v.y; az += v.z; aw += v.w;
    l += lP[(size_t)(c * 8 + bh) * NN + n];
  }
  const float inv = 1.0f / l;
  bf16x4 o;
  o[0] = (short)f2bf(ax * inv);
  o[1] = (short)f2bf(ay * inv);
  o[2] = (short)f2bf(az * inv);
  o[3] = (short)f2bf(aw * inv);
  *(bf16x4*)&ob[((size_t)b * NN + n) * DIM + h * HD + d4] = o;
}

// ---------------------------------------------------------------------------
extern "C" void kernel_launch(void* const* d_in, const int* in_sizes, int n_in,
                              void* d_out, int out_size, void* d_ws, size_t ws_size,
                              hipStream_t stream) {
  const float* x = (const float*)d_in[0];
  const float* pos = (const float*)d_in[1];
  const float* Wq_w = (const float*)d_in[2];
  const float* Wq_b = (const float*)d_in[3];
  const float* Wk_w = (const float*)d_in[4];
  const float* Wk_b = (const float*)d_in[5];
  const float* Wv_w = (const float*)d_in[6];
  const float* Wv_b = (const float*)d_in[7];
  const float* Wo_w = (const float*)d_in[8];
  const float* Wo_b = (const float*)d_in[9];
  const float* n1_g = (const float*)d_in[10];
  const float* n1_b = (const float*)d_in[11];
  const float* n2_g = (const float*)d_in[12];
  const float* n2_b = (const float*)d_in[13];
  const float* l1_w = (const float*)d_in[14];
  const float* l1_b = (const float*)d_in[15];
  const float* l2_w = (const float*)d_in[16];
  const float* l2_b = (const float*)d_in[17];

  float* out = (float*)d_out;
  short* wsS = (short*)d_ws;
  const size_t MN = (size_t)MROWS * DIM;   // 1048576
  // shorts region: q,k,vt,ob + wT  (~8.9 MB)
  short* qb_bf = wsS;                      // q [M][128], k at +MN, vt at +2MN
  short* ob_bf = wsS + 3 * MN;             // [M][128]
  short* wT    = wsS + 4 * MN;             // 262144 shorts
  // floats region
  float* fbase = (float*)(wsS + 4 * MN + 262144);
  float* qkvb  = fbase;                    // 768
  float* sums  = fbase + 768;              // 1280 (5 slots x 256)
  float* lP    = fbase + 2048;             // NCH*8*NN = 131072
  float* accP  = fbase + 2048 + 131072;    // NCH*8*NN*HD = 4194304
  float* pposG = accP + 4194304;           // B*N*4 = 32768 floats
  short* hb_bf = (short*)accP;             // FFN hidden aliases accP (disjoint phases)

  wprep_k<<<256, 256, 0, stream>>>(Wq_w, Wk_w, Wv_w, Wo_w, l1_w, l2_w,
                                   Wq_b, Wk_b, Wv_b, wT, qkvb);
  hipMemsetAsync(sums, 0, 1280 * sizeof(float), stream);
  copy_stats_k<<<256, 256, 0, stream>>>(x, out, sums, pos, pposG);  // slot 0 = n1, l0

  for (int l = 0; l < LYR; l++) {
    const short* lw = wT + (size_t)l * 131072;
    float* s_n1 = sums + (2 * l) * 256;
    float* s_n2 = sums + (2 * l + 1) * 256;
    float* s_nx = sums + (2 * l + 2) * 256;   // next layer's n1 (or dummy)

    // --- attention block (BN fused into QKV GEMM A-load) ---
    gemm_bf_k<3, false, true><<<dim3(128, 6), 256, 0, stream>>>(
        nullptr, out, s_n1, n1_g + l * DIM, n1_b + l * DIM,
        lw, qkvb + l * 384, nullptr, nullptr, qb_bf, nullptr, 128);
    if (l == 0) rope_bf_k<<<128, 256, 0, stream>>>(qb_bf, qb_bf + MN, pos);
    attn5_k<<<dim3(NN / 128, BB * NH, NCH), 256, 0, stream>>>(
        qb_bf, qb_bf + MN, qb_bf + 2 * MN, pposG, accP, lP);
    attn_comb_k<<<1024, 256, 0, stream>>>(accP, lP, ob_bf);
    gemm_bf_k<0, false, false><<<dim3(128, 2), 256, 0, stream>>>(
        ob_bf, nullptr, nullptr, nullptr, nullptr,
        lw + 49152, Wo_b + l * DIM, out, out, nullptr, s_n2, 128);

    // --- FFN block (BN fused into FFN1 GEMM A-load) ---
    gemm_bf_k<1, true, true><<<dim3(128, 4), 256, 0, stream>>>(
        nullptr, out, s_n2, n2_g + l * DIM, n2_b + l * DIM,
        lw + 65536, l1_b + l * 2 * DIM, nullptr, nullptr, hb_bf, nullptr, 128);
    gemm_bf_k<0, false, false><<<dim3(128, 2), 256, 0, stream>>>(
        hb_bf, nullptr, nullptr, nullptr, nullptr,
        lw + 98304, l2_b + l * DIM, out, out, nullptr, s_nx, 256);
  }
}